// Round 4
// baseline (967.190 us; speedup 1.0000x reference)
//
#include <hip/hip_runtime.h>
#include <math.h>

// ---------------- bf16 helpers ----------------
__device__ __forceinline__ float bflo(unsigned u){ return __int_as_float(u << 16); }
__device__ __forceinline__ float bfhi(unsigned u){ return __int_as_float(u & 0xffff0000u); }
__device__ __forceinline__ unsigned f2bf_u(float x){
  unsigned u = __float_as_uint(x);
  return (u + 0x7fffu + ((u >> 16) & 1u)) >> 16;
}
__device__ __forceinline__ unsigned packbf2(float a, float b){
  return f2bf_u(a) | (f2bf_u(b) << 16);
}

// ---------------- wave helpers (wave = 64 on gfx950) ----------------
__device__ __forceinline__ float wmaxf(float v){
#pragma unroll
  for (int off = 1; off < 64; off <<= 1) v = fmaxf(v, __shfl_xor(v, off, 64));
  return v;
}
__device__ __forceinline__ float wsumf(float v){
#pragma unroll
  for (int off = 1; off < 64; off <<= 1) v += __shfl_xor(v, off, 64);
  return v;
}

// ---------------- CSR build ----------------
__global__ void k_zero2(int* __restrict__ a, int* __restrict__ b, int n){
  int i = blockIdx.x * blockDim.x + threadIdx.x;
  if (i < n){ a[i] = 0; b[i] = 0; }
}

__global__ void k_hist(const int* __restrict__ dst, int* __restrict__ cnt, int E){
  int i = blockIdx.x * blockDim.x + threadIdx.x;
  if (i < E) atomicAdd(&cnt[dst[i]], 1);
}

__global__ void k_scan1(const int* __restrict__ cnt, int* __restrict__ ptre,
                        int* __restrict__ sums, int n){
  __shared__ int sh[256];
  int t = threadIdx.x; int i = blockIdx.x * 256 + t;
  int v = (i < n) ? cnt[i] : 0;
  sh[t] = v; __syncthreads();
  for (int off = 1; off < 256; off <<= 1){
    int u = (t >= off) ? sh[t - off] : 0;
    __syncthreads();
    sh[t] += u;
    __syncthreads();
  }
  if (i < n) ptre[i] = sh[t] - v;
  if (t == 255) sums[blockIdx.x] = sh[255];
}

__global__ void k_scan2(const int* __restrict__ sums, int* __restrict__ chof, int nch){
  __shared__ int sh[256];
  int t = threadIdx.x;
  int v = (t < nch) ? sums[t] : 0;
  sh[t] = v; __syncthreads();
  for (int off = 1; off < 256; off <<= 1){
    int u = (t >= off) ? sh[t - off] : 0;
    __syncthreads();
    sh[t] += u;
    __syncthreads();
  }
  if (t < nch) chof[t] = sh[t] - v;
}

__global__ void k_scan3(int* __restrict__ ptre, const int* __restrict__ chof, int n, int E){
  int i = blockIdx.x * 256 + threadIdx.x;
  if (i < n) ptre[i] += chof[blockIdx.x];
  if (blockIdx.x == 0 && threadIdx.x == 0) ptre[n] = E;
}

__global__ void k_fill(const int* __restrict__ src, const int* __restrict__ dst,
                       const int* __restrict__ ptre, int* __restrict__ fpos,
                       int* __restrict__ srcs, int E){
  int i = blockIdx.x * blockDim.x + threadIdx.x;
  if (i < E){
    int d = dst[i];
    int pos = ptre[d] + atomicAdd(&fpos[d], 1);
    srcs[pos] = src[i];
  }
}

__global__ void k_pack(const int* __restrict__ srcs, const float* __restrict__ wE,
                       int2* __restrict__ epk, int E){
  int i = blockIdx.x * blockDim.x + threadIdx.x;
  if (i < E) epk[i] = make_int2(srcs[i], __float_as_int(wE[i]));
}

// ---------------- dense GEMM: Yb[n,MDIM](bf16) = X[n,K] @ W[K,MDIM] --------
template<int MDIM>
__global__ __launch_bounds__(256) void k_gemm(
    const float* __restrict__ X, const float* __restrict__ W,
    unsigned int* __restrict__ Yb, int n, int K)
{
  constexpr int CO = MDIM / 4;
  constexpr int RO = 256 / CO;
  constexpr int RT = 64 / RO;
  __shared__ float xs[32][68];
  __shared__ float wsh[32][MDIM];
  int tid = threadIdx.x;
  int c = tid % CO, r = tid / CO;
  int n0 = blockIdx.x * 64;
  float acc[RT][4];
#pragma unroll
  for (int i = 0; i < RT; i++)
#pragma unroll
    for (int j = 0; j < 4; j++) acc[i][j] = 0.f;
  int lrow = tid & 63;
  int kq4 = (tid >> 6) << 2;
  for (int k0 = 0; k0 < K; k0 += 32){
    const float* Xr = X + (size_t)min(n0 + lrow, n - 1) * K + k0 + kq4;
#pragma unroll
    for (int kb = 0; kb < 32; kb += 16){
      float4 xv = *reinterpret_cast<const float4*>(Xr + kb);
      xs[kb + kq4 + 0][lrow] = xv.x;
      xs[kb + kq4 + 1][lrow] = xv.y;
      xs[kb + kq4 + 2][lrow] = xv.z;
      xs[kb + kq4 + 3][lrow] = xv.w;
    }
#pragma unroll
    for (int t = 0; t < MDIM / 32; t++){
      int idx = (tid + t * 256) * 4;
      int kk = idx / MDIM, mm = idx % MDIM;
      *reinterpret_cast<float4*>(&wsh[kk][mm]) =
          *reinterpret_cast<const float4*>(W + (size_t)(k0 + kk) * MDIM + mm);
    }
    __syncthreads();
#pragma unroll
    for (int kk = 0; kk < 32; kk++){
      float4 b = *reinterpret_cast<float4*>(&wsh[kk][4 * c]);
      float a[RT];
#pragma unroll
      for (int i = 0; i < RT; i += 4){
        float4 av = *reinterpret_cast<float4*>(&xs[kk][RT * r + i]);
        a[i] = av.x; a[i + 1] = av.y; a[i + 2] = av.z; a[i + 3] = av.w;
      }
#pragma unroll
      for (int i = 0; i < RT; i++){
        acc[i][0] += a[i] * b.x;
        acc[i][1] += a[i] * b.y;
        acc[i][2] += a[i] * b.z;
        acc[i][3] += a[i] * b.w;
      }
    }
    __syncthreads();
  }
#pragma unroll
  for (int i = 0; i < RT; i++){
    int gr = n0 + RT * r + i;
    if (gr < n){
      uint2 pk = make_uint2(packbf2(acc[i][0], acc[i][1]),
                            packbf2(acc[i][2], acc[i][3]));
      *reinterpret_cast<uint2*>((unsigned short*)Yb + (size_t)gr * MDIM + 4 * c) = pk;
    }
  }
}

// ---------------- el/er from bf16 h ----------------
template<int HNUM, int HIDD>
__global__ void k_elr(const unsigned int* __restrict__ hb, const float* __restrict__ al,
                      const float* __restrict__ ar, float* __restrict__ el,
                      float* __restrict__ er, int n)
{
  int idx = blockIdx.x * blockDim.x + threadIdx.x;
  if (idx >= n * HNUM) return;
  int node = idx / HNUM, hh = idx - node * HNUM;
  const uint2* row = reinterpret_cast<const uint2*>(
      (const unsigned short*)hb + (size_t)node * (HNUM * HIDD) + hh * HIDD);
  const float4* a4 = reinterpret_cast<const float4*>(al + hh * HIDD);
  const float4* r4 = reinterpret_cast<const float4*>(ar + hh * HIDD);
  float se = 0.f, sr = 0.f;
#pragma unroll
  for (int d = 0; d < HIDD / 4; d++){
    uint2 u = row[d];
    float v0 = bflo(u.x), v1 = bfhi(u.x), v2 = bflo(u.y), v3 = bfhi(u.y);
    float4 x = a4[d], y = r4[d];
    se += v0 * x.x + v1 * x.y + v2 * x.z + v3 * x.w;
    sr += v0 * y.x + v1 * y.y + v2 * y.z + v3 * y.w;
  }
  el[idx] = se; er[idx] = sr;
}

// ---------------- edge softmax + aggregation (one wave per dst node) --------
// bf16 h gathers (16B uint4 per lane), fp32 accumulate.
// EPI: 0 = ELU store fp32 [N,MDIM]; 1 = softmax -> bf16 pseudo [N,64].
template<int HNUM, int MDIM, int EPI>
__global__ __launch_bounds__(64) void k_edge(
    const int* __restrict__ ptre, const int* __restrict__ srcs,
    const uint4* __restrict__ hb, const float* __restrict__ el,
    const float* __restrict__ er, float* __restrict__ outp,
    unsigned int* __restrict__ outb, float* __restrict__ wE, int init_w, int n)
{
  constexpr int LL = MDIM / 8;
  constexpr int EP = 64 / LL;
  constexpr int RS = MDIM / 8;
  __shared__ float alds[128 * HNUM];
  __shared__ int   sids[128];
  int node = blockIdx.x;
  if (node >= n) return;
  int lane = threadIdx.x;
  int base = ptre[node];
  int deg  = ptre[node + 1] - base;

  float erv[HNUM];
  if (HNUM == 4){
    float4 t = *reinterpret_cast<const float4*>(er + node * 4);
    erv[0] = t.x; erv[1] = t.y; erv[2] = t.z; erv[3] = t.w;
  } else erv[0] = er[node];

  float mx[HNUM], sm[HNUM];
#pragma unroll
  for (int h = 0; h < HNUM; h++){ mx[h] = -INFINITY; sm[h] = 0.f; }
  for (int i = lane; i < deg; i += 64){
    int s = srcs[base + i];
    float e[HNUM];
    if (HNUM == 4){
      float4 t = *reinterpret_cast<const float4*>(el + s * 4);
      e[0] = t.x; e[1] = t.y; e[2] = t.z; e[3] = t.w;
    } else e[0] = el[s];
#pragma unroll
    for (int h = 0; h < HNUM; h++){
      float v = e[h] + erv[h];
      v = v > 0.f ? v : 0.2f * v;
      float mn = fmaxf(mx[h], v);
      sm[h] = sm[h] * __expf(mx[h] - mn) + __expf(v - mn);
      mx[h] = mn;
    }
  }
  float M[HNUM], inv[HNUM];
#pragma unroll
  for (int h = 0; h < HNUM; h++){
    M[h] = wmaxf(mx[h]);
    float sc = sm[h] * __expf(mx[h] - M[h]);
    inv[h] = 1.f / (wsumf(sc) + 1e-9f);
  }

  int l = lane % LL, g = lane / LL;
  float acc[8];
#pragma unroll
  for (int d = 0; d < 8; d++) acc[d] = 0.f;

  for (int c0 = 0; c0 < deg; c0 += 128){
    int cnt = min(128, deg - c0);
    for (int i = lane; i < cnt; i += 64){
      int s = srcs[base + c0 + i];
      sids[i] = s;
      float e[HNUM], a[HNUM], wsum = 0.f;
      if (HNUM == 4){
        float4 t = *reinterpret_cast<const float4*>(el + s * 4);
        e[0] = t.x; e[1] = t.y; e[2] = t.z; e[3] = t.w;
      } else e[0] = el[s];
#pragma unroll
      for (int h = 0; h < HNUM; h++){
        float v = e[h] + erv[h];
        v = v > 0.f ? v : 0.2f * v;
        a[h] = __expf(v - M[h]) * inv[h];
        wsum += a[h];
      }
      if (HNUM == 4)
        *reinterpret_cast<float4*>(&alds[i * 4]) = make_float4(a[0], a[1], a[2], a[3]);
      else
        alds[i] = a[0];
      wsum *= (1.f / (3.f * HNUM));
      int eidx = base + c0 + i;
      wE[eidx] = init_w ? wsum : (wE[eidx] + wsum);
    }
    __syncthreads();
    for (int j0 = 0; j0 < cnt; j0 += EP){
      int j = j0 + g;
      if (j < cnt){
        int s = sids[j];
        float a = (HNUM == 4) ? alds[j * 4 + (l >> 2)] : alds[j];
        uint4 v = hb[(size_t)s * RS + l];
        acc[0] += a * bflo(v.x); acc[1] += a * bfhi(v.x);
        acc[2] += a * bflo(v.y); acc[3] += a * bfhi(v.y);
        acc[4] += a * bflo(v.z); acc[5] += a * bfhi(v.z);
        acc[6] += a * bflo(v.w); acc[7] += a * bfhi(v.w);
      }
    }
    __syncthreads();
  }
#pragma unroll
  for (int off = LL; off < 64; off <<= 1)
#pragma unroll
    for (int d = 0; d < 8; d++) acc[d] += __shfl_xor(acc[d], off, 64);

  if (EPI == 0){
    if (g == 0){
      float o[8];
#pragma unroll
      for (int d = 0; d < 8; d++) o[d] = acc[d] > 0.f ? acc[d] : expm1f(acc[d]);
      float4* dst4 = reinterpret_cast<float4*>(outp + (size_t)node * MDIM + 8 * l);
      dst4[0] = make_float4(o[0], o[1], o[2], o[3]);
      dst4[1] = make_float4(o[4], o[5], o[6], o[7]);
    }
  } else {
    float m8 = acc[0];
#pragma unroll
    for (int d = 1; d < 8; d++) m8 = fmaxf(m8, acc[d]);
#pragma unroll
    for (int off = 1; off < 8; off <<= 1) m8 = fmaxf(m8, __shfl_xor(m8, off, 64));
    float p[8], s8 = 0.f;
#pragma unroll
    for (int d = 0; d < 8; d++){ p[d] = __expf(acc[d] - m8); s8 += p[d]; }
#pragma unroll
    for (int off = 1; off < 8; off <<= 1) s8 += __shfl_xor(s8, off, 64);
    float is = 1.f / s8;
    if (g == 0){
      uint4 pk;
      pk.x = packbf2(p[0] * is, p[1] * is);
      pk.y = packbf2(p[2] * is, p[3] * is);
      pk.z = packbf2(p[4] * is, p[5] * is);
      pk.w = packbf2(p[6] * is, p[7] * is);
      *reinterpret_cast<uint4*>((unsigned short*)outb + (size_t)node * 64 + 8 * l) = pk;
    }
  }
}

// ---------------- fused LP step: gather-agg + Wp linear + softmax -----------
// 4 nodes/block (1 wave each). Wp staged in LDS. final: log-softmax fp32 out.
__global__ __launch_bounds__(256) void k_lp(
    const int* __restrict__ ptre, const int2* __restrict__ epk,
    const uint4* __restrict__ pb, const float* __restrict__ Wp,
    const float* __restrict__ bp, unsigned int* __restrict__ outb,
    float* __restrict__ outf, int final_step, int n)
{
  __shared__ float wsh[64][68];
  __shared__ float ash[4][64];
  __shared__ float bsh[64];
  int tid = threadIdx.x;
  // stage Wp (row-major [k][c]) + bias
  for (int i = tid; i < 1024; i += 256){
    int e = i * 4; int k = e >> 6, c = e & 63;
    *reinterpret_cast<float4*>(&wsh[k][c]) = reinterpret_cast<const float4*>(Wp)[i];
  }
  if (tid < 64) bsh[tid] = bp[tid];

  int w = tid >> 6, lane = tid & 63;
  int node = blockIdx.x * 4 + w;
  int l = lane & 7, g = lane >> 3;
  if (node < n){
    int base = ptre[node], deg = ptre[node + 1] - base;
    float acc[8];
#pragma unroll
    for (int d = 0; d < 8; d++) acc[d] = 0.f;
    for (int j0 = 0; j0 < deg; j0 += 8){
      int j = j0 + g;
      if (j < deg){
        int2 ep = epk[base + j];
        float wv = __int_as_float(ep.y);
        uint4 v = pb[(size_t)ep.x * 8 + l];
        acc[0] += wv * bflo(v.x); acc[1] += wv * bfhi(v.x);
        acc[2] += wv * bflo(v.y); acc[3] += wv * bfhi(v.y);
        acc[4] += wv * bflo(v.z); acc[5] += wv * bfhi(v.z);
        acc[6] += wv * bflo(v.w); acc[7] += wv * bfhi(v.w);
      }
    }
#pragma unroll
    for (int off = 8; off < 64; off <<= 1)
#pragma unroll
      for (int d = 0; d < 8; d++) acc[d] += __shfl_xor(acc[d], off, 64);
    if (g == 0){
      *reinterpret_cast<float4*>(&ash[w][8 * l]) = make_float4(acc[0], acc[1], acc[2], acc[3]);
      *reinterpret_cast<float4*>(&ash[w][8 * l + 4]) = make_float4(acc[4], acc[5], acc[6], acc[7]);
    }
  }
  __syncthreads();
  if (node >= n) return;
  int c = lane;
  float lg = bsh[c];
#pragma unroll 4
  for (int k0 = 0; k0 < 64; k0 += 4){
    float4 av = *reinterpret_cast<float4*>(&ash[w][k0]);
    lg += av.x * wsh[k0][c] + av.y * wsh[k0 + 1][c]
        + av.z * wsh[k0 + 2][c] + av.w * wsh[k0 + 3][c];
  }
  float m = wmaxf(lg);
  float p = __expf(lg - m);
  float s = wsumf(p);
  if (final_step){
    outf[(size_t)node * 64 + c] = (lg - m) - __logf(s);
  } else {
    float v = p / s;
    float vn = __shfl_xor(v, 1, 64);
    if ((c & 1) == 0)
      ((unsigned int*)outb)[((size_t)node * 64 + c) >> 1] = packbf2(v, vn);
  }
}

// ---------------- launch ----------------
extern "C" void kernel_launch(void* const* d_in, const int* in_sizes, int n_in,
                              void* d_out, int out_size, void* d_ws, size_t ws_size,
                              hipStream_t stream) {
  const float* feat = (const float*)d_in[0];
  const int*   src  = (const int*)d_in[1];
  const int*   dst  = (const int*)d_in[2];
  const float* W0   = (const float*)d_in[3];
  const float* al0  = (const float*)d_in[4];
  const float* ar0  = (const float*)d_in[5];
  const float* W1   = (const float*)d_in[6];
  const float* al1  = (const float*)d_in[7];
  const float* ar1  = (const float*)d_in[8];
  const float* W2   = (const float*)d_in[9];
  const float* al2  = (const float*)d_in[10];
  const float* ar2  = (const float*)d_in[11];
  const float* Wp   = (const float*)d_in[12];
  const float* bp   = (const float*)d_in[13];
  float* out = (float*)d_out;

  const int N = in_sizes[0] / 256;
  const int E = in_sizes[1];
  const int NCH = (N + 255) / 256;

  char* p = (char*)d_ws;
  auto carve = [&](size_t bytes) -> void* {
    void* r = (void*)p;
    p += (bytes + 255) & ~(size_t)255;
    return r;
  };
  int*   ptr_i = (int*)carve((size_t)(N + 1) * 4);
  int*   cntA  = (int*)carve((size_t)N * 4);
  int*   cntB  = (int*)carve((size_t)N * 4);
  int*   sums  = (int*)carve(1024);
  int*   chof  = (int*)carve(1024);
  int*   srcs  = (int*)carve((size_t)E * 4);
  float* wE    = (float*)carve((size_t)E * 4);
  float* xbuf  = (float*)carve((size_t)N * 128 * 4);   // fp32 ELU out / epk overlay
  unsigned int* hb = (unsigned int*)carve((size_t)N * 128 * 2);   // bf16 h
  float* el    = (float*)carve((size_t)N * 4 * 4);
  float* er    = (float*)carve((size_t)N * 4 * 4);
  unsigned int* pbA = (unsigned int*)carve((size_t)N * 64 * 2);   // bf16 pseudo
  unsigned int* pbB = (unsigned int*)carve((size_t)N * 64 * 2);
  int2*  epk = (int2*)xbuf;    // overlays xbuf (dead after layer-2 GEMM)
  (void)ws_size; (void)n_in; (void)out_size;

  // ---- CSR by dst ----
  k_zero2<<<(N + 255) / 256, 256, 0, stream>>>(cntA, cntB, N);
  k_hist<<<(E + 255) / 256, 256, 0, stream>>>(dst, cntA, E);
  k_scan1<<<NCH, 256, 0, stream>>>(cntA, ptr_i, sums, N);
  k_scan2<<<1, 256, 0, stream>>>(sums, chof, NCH);
  k_scan3<<<NCH, 256, 0, stream>>>(ptr_i, chof, N, E);
  k_fill<<<(E + 255) / 256, 256, 0, stream>>>(src, dst, ptr_i, cntB, srcs, E);

  const int GG = (N + 63) / 64;
  // ---- layer 0: 256 -> [4,32] ----
  k_gemm<128><<<GG, 256, 0, stream>>>(feat, W0, hb, N, 256);
  k_elr<4, 32><<<(N * 4 + 255) / 256, 256, 0, stream>>>(hb, al0, ar0, el, er, N);
  k_edge<4, 128, 0><<<N, 64, 0, stream>>>(ptr_i, srcs, (const uint4*)hb, el, er, xbuf, nullptr, wE, 1, N);
  // ---- layer 1: 128 -> [4,32] ----
  k_gemm<128><<<GG, 256, 0, stream>>>(xbuf, W1, hb, N, 128);
  k_elr<4, 32><<<(N * 4 + 255) / 256, 256, 0, stream>>>(hb, al1, ar1, el, er, N);
  k_edge<4, 128, 0><<<N, 64, 0, stream>>>(ptr_i, srcs, (const uint4*)hb, el, er, xbuf, nullptr, wE, 0, N);
  // ---- layer 2: 128 -> [1,64] ----
  k_gemm<64><<<GG, 256, 0, stream>>>(xbuf, W2, hb, N, 128);
  k_elr<1, 64><<<(N + 255) / 256, 256, 0, stream>>>(hb, al2, ar2, el, er, N);
  k_edge<1, 64, 1><<<N, 64, 0, stream>>>(ptr_i, srcs, (const uint4*)hb, el, er, nullptr, pbA, wE, 0, N);

  // ---- pack (src, w) for LP gathers ----
  k_pack<<<(E + 255) / 256, 256, 0, stream>>>(srcs, wE, epk, E);

  // ---- 10 fused label-prop steps ----
  unsigned int* cur = pbA; unsigned int* nxt = pbB;
  for (int st = 0; st < 10; st++){
    k_lp<<<(N + 3) / 4, 256, 0, stream>>>(ptr_i, epk, (const uint4*)cur, Wp, bp,
                                          nxt, out, st == 9, N);
    unsigned int* t = cur; cur = nxt; nxt = t;
  }
}

// Round 5
// 706.175 us; speedup vs baseline: 1.3696x; 1.3696x over previous
//
#include <hip/hip_runtime.h>
#include <math.h>

typedef __attribute__((ext_vector_type(8))) short short8;
typedef __attribute__((ext_vector_type(4))) float f32x4;

// ---------------- bf16 helpers ----------------
__device__ __forceinline__ float bflo(unsigned u){ return __int_as_float(u << 16); }
__device__ __forceinline__ float bfhi(unsigned u){ return __int_as_float(u & 0xffff0000u); }
__device__ __forceinline__ unsigned f2bf_u(float x){
  unsigned u = __float_as_uint(x);
  return (u + 0x7fffu + ((u >> 16) & 1u)) >> 16;
}
__device__ __forceinline__ unsigned packbf2(float a, float b){
  return f2bf_u(a) | (f2bf_u(b) << 16);
}

// ---------------- wave helpers (wave = 64 on gfx950) ----------------
__device__ __forceinline__ float wmaxf(float v){
#pragma unroll
  for (int off = 1; off < 64; off <<= 1) v = fmaxf(v, __shfl_xor(v, off, 64));
  return v;
}
__device__ __forceinline__ float wsumf(float v){
#pragma unroll
  for (int off = 1; off < 64; off <<= 1) v += __shfl_xor(v, off, 64);
  return v;
}

// ---------------- CSR build ----------------
__global__ void k_zero2(int* __restrict__ a, int* __restrict__ b, int n){
  int i = blockIdx.x * blockDim.x + threadIdx.x;
  if (i < n){ a[i] = 0; b[i] = 0; }
}

__global__ void k_hist(const int* __restrict__ dst, int* __restrict__ cnt, int E){
  int i = blockIdx.x * blockDim.x + threadIdx.x;
  if (i < E) atomicAdd(&cnt[dst[i]], 1);
}

__global__ void k_scan1(const int* __restrict__ cnt, int* __restrict__ ptre,
                        int* __restrict__ sums, int n){
  __shared__ int sh[256];
  int t = threadIdx.x; int i = blockIdx.x * 256 + t;
  int v = (i < n) ? cnt[i] : 0;
  sh[t] = v; __syncthreads();
  for (int off = 1; off < 256; off <<= 1){
    int u = (t >= off) ? sh[t - off] : 0;
    __syncthreads();
    sh[t] += u;
    __syncthreads();
  }
  if (i < n) ptre[i] = sh[t] - v;
  if (t == 255) sums[blockIdx.x] = sh[255];
}

__global__ void k_scan2(const int* __restrict__ sums, int* __restrict__ chof, int nch){
  __shared__ int sh[256];
  int t = threadIdx.x;
  int v = (t < nch) ? sums[t] : 0;
  sh[t] = v; __syncthreads();
  for (int off = 1; off < 256; off <<= 1){
    int u = (t >= off) ? sh[t - off] : 0;
    __syncthreads();
    sh[t] += u;
    __syncthreads();
  }
  if (t < nch) chof[t] = sh[t] - v;
}

__global__ void k_scan3(int* __restrict__ ptre, const int* __restrict__ chof, int n, int E){
  int i = blockIdx.x * 256 + threadIdx.x;
  if (i < n) ptre[i] += chof[blockIdx.x];
  if (blockIdx.x == 0 && threadIdx.x == 0) ptre[n] = E;
}

__global__ void k_fill(const int* __restrict__ src, const int* __restrict__ dst,
                       const int* __restrict__ ptre, int* __restrict__ fpos,
                       int* __restrict__ srcs, int E){
  int i = blockIdx.x * blockDim.x + threadIdx.x;
  if (i < E){
    int d = dst[i];
    int pos = ptre[d] + atomicAdd(&fpos[d], 1);
    srcs[pos] = src[i];
  }
}

__global__ void k_pack(const int* __restrict__ srcs, const float* __restrict__ wE,
                       int2* __restrict__ epk, int E){
  int i = blockIdx.x * blockDim.x + threadIdx.x;
  if (i < E) epk[i] = make_int2(srcs[i], __float_as_int(wE[i]));
}

// ---------------- weight convert + transpose to bf16 [N][K] ----------------
__global__ void k_cvtw(const float* __restrict__ W0, const float* __restrict__ W1,
                       const float* __restrict__ W2, const float* __restrict__ Wp,
                       unsigned short* __restrict__ T0, unsigned short* __restrict__ T1,
                       unsigned short* __restrict__ T2, unsigned short* __restrict__ Tp){
  int i = blockIdx.x * 256 + threadIdx.x;
  const float* src; unsigned short* dst; int NN, KK, idx;
  if (i < 32768){ src = W0; dst = T0; NN = 128; KK = 256; idx = i; }
  else if (i < 49152){ src = W1; dst = T1; NN = 128; KK = 128; idx = i - 32768; }
  else if (i < 57344){ src = W2; dst = T2; NN = 64; KK = 128; idx = i - 49152; }
  else { src = Wp; dst = Tp; NN = 64; KK = 64; idx = i - 57344; }
  int nn = idx / KK, kk = idx - nn * KK;
  dst[idx] = (unsigned short)f2bf_u(src[(size_t)kk * NN + nn]);
}

// ---------------- MFMA GEMM: Y[n,NC] = X[n,KD] @ W[KD,NC] -------------------
// X bf16 (or fp32 when XF32), Wt = bf16 transposed [NC][KD].
// EPI 0: bf16 store; EPI 1: +bias row softmax -> bf16; EPI 2: +bias row
// log-softmax -> fp32 (NC=64 for EPI>0). Block: 256 thr, 64 rows, all NC cols.
template<int NC, int EPI, bool XF32>
__global__ __launch_bounds__(256) void k_gemm_m(
    const void* __restrict__ Xv, const unsigned short* __restrict__ Wt,
    const float* __restrict__ bias, unsigned short* __restrict__ Yb,
    float* __restrict__ Yf, int n, int KD)
{
  constexpr int CT = NC / 16;
  __shared__ __align__(16) unsigned short xs[64 * 72];
  __shared__ __align__(16) unsigned short ws[NC * 72];
  __shared__ float bsh[64];
  int tid = threadIdx.x;
  int w = tid >> 6, lane = tid & 63;
  int m = lane & 15, q = lane >> 4;
  int n0 = blockIdx.x * 64;
  f32x4 acc[CT];
#pragma unroll
  for (int ct = 0; ct < CT; ct++) acc[ct] = (f32x4){0.f, 0.f, 0.f, 0.f};
  if (EPI != 0 && tid < 64) bsh[tid] = bias[tid];

  for (int kc = 0; kc < KD; kc += 64){
    if (XF32){
      const float* X = (const float*)Xv;
#pragma unroll
      for (int s = tid; s < 512; s += 256){
        int r = s >> 3, off = (s & 7) * 8;
        int gr = min(n0 + r, n - 1);
        const float4* g = (const float4*)(X + (size_t)gr * KD + kc + off);
        float4 v0 = g[0], v1 = g[1];
        uint4 pk = make_uint4(packbf2(v0.x, v0.y), packbf2(v0.z, v0.w),
                              packbf2(v1.x, v1.y), packbf2(v1.z, v1.w));
        *(uint4*)&xs[r * 72 + off] = pk;
      }
    } else {
      const unsigned short* X = (const unsigned short*)Xv;
#pragma unroll
      for (int s = tid; s < 512; s += 256){
        int r = s >> 3, off = (s & 7) * 8;
        int gr = min(n0 + r, n - 1);
        *(uint4*)&xs[r * 72 + off] = *(const uint4*)(X + (size_t)gr * KD + kc + off);
      }
    }
#pragma unroll
    for (int s = tid; s < NC * 8; s += 256){
      int r = s >> 3, off = (s & 7) * 8;
      *(uint4*)&ws[r * 72 + off] = *(const uint4*)(Wt + (size_t)r * KD + kc + off);
    }
    __syncthreads();
    short8 a0 = *(const short8*)&xs[(16 * w + m) * 72 + q * 8];
    short8 a1 = *(const short8*)&xs[(16 * w + m) * 72 + 32 + q * 8];
#pragma unroll
    for (int ct = 0; ct < CT; ct++){
      short8 b0 = *(const short8*)&ws[(16 * ct + m) * 72 + q * 8];
      short8 b1 = *(const short8*)&ws[(16 * ct + m) * 72 + 32 + q * 8];
      acc[ct] = __builtin_amdgcn_mfma_f32_16x16x32_bf16(a0, b0, acc[ct], 0, 0, 0);
      acc[ct] = __builtin_amdgcn_mfma_f32_16x16x32_bf16(a1, b1, acc[ct], 0, 0, 0);
    }
    __syncthreads();
  }

  if (EPI == 0){
#pragma unroll
    for (int j = 0; j < 4; j++){
      int gr = n0 + 16 * w + q * 4 + j;
      if (gr < n){
#pragma unroll
        for (int ct = 0; ct < CT; ct++)
          Yb[(size_t)gr * NC + 16 * ct + m] = (unsigned short)f2bf_u(acc[ct][j]);
      }
    }
  } else {
#pragma unroll
    for (int j = 0; j < 4; j++){
      int gr = n0 + 16 * w + q * 4 + j;
      float v[CT];
      float mx = -INFINITY;
#pragma unroll
      for (int ct = 0; ct < CT; ct++){
        v[ct] = acc[ct][j] + bsh[16 * ct + m];
        mx = fmaxf(mx, v[ct]);
      }
#pragma unroll
      for (int off = 1; off < 16; off <<= 1) mx = fmaxf(mx, __shfl_xor(mx, off, 64));
      float p[CT], s = 0.f;
#pragma unroll
      for (int ct = 0; ct < CT; ct++){ p[ct] = __expf(v[ct] - mx); s += p[ct]; }
#pragma unroll
      for (int off = 1; off < 16; off <<= 1) s += __shfl_xor(s, off, 64);
      if (gr < n){
        if (EPI == 1){
          float is = 1.f / s;
#pragma unroll
          for (int ct = 0; ct < CT; ct++)
            Yb[(size_t)gr * 64 + 16 * ct + m] = (unsigned short)f2bf_u(p[ct] * is);
        } else {
          float ls = __logf(s);
#pragma unroll
          for (int ct = 0; ct < CT; ct++)
            Yf[(size_t)gr * 64 + 16 * ct + m] = v[ct] - mx - ls;
        }
      }
    }
  }
}

// ---------------- el/er from bf16 h ----------------
template<int HNUM, int HIDD>
__global__ void k_elr(const unsigned short* __restrict__ hb, const float* __restrict__ al,
                      const float* __restrict__ ar, float* __restrict__ el,
                      float* __restrict__ er, int n)
{
  int idx = blockIdx.x * blockDim.x + threadIdx.x;
  if (idx >= n * HNUM) return;
  int node = idx / HNUM, hh = idx - node * HNUM;
  const uint2* row = reinterpret_cast<const uint2*>(hb + (size_t)node * (HNUM * HIDD) + hh * HIDD);
  const float4* a4 = reinterpret_cast<const float4*>(al + hh * HIDD);
  const float4* r4 = reinterpret_cast<const float4*>(ar + hh * HIDD);
  float se = 0.f, sr = 0.f;
#pragma unroll
  for (int d = 0; d < HIDD / 4; d++){
    uint2 u = row[d];
    float v0 = bflo(u.x), v1 = bfhi(u.x), v2 = bflo(u.y), v3 = bfhi(u.y);
    float4 x = a4[d], y = r4[d];
    se += v0 * x.x + v1 * x.y + v2 * x.z + v3 * x.w;
    sr += v0 * y.x + v1 * y.y + v2 * y.z + v3 * y.w;
  }
  el[idx] = se; er[idx] = sr;
}

// ---------------- edge softmax + aggregation (one wave per dst node) --------
// bf16 h gathers, fp32 accumulate.
// EPI 0: ELU -> bf16 [N,MDIM]; EPI 1: softmax -> bf16 pseudo [N,64].
template<int HNUM, int MDIM, int EPI>
__global__ __launch_bounds__(64) void k_edge(
    const int* __restrict__ ptre, const int* __restrict__ srcs,
    const uint4* __restrict__ hb, const float* __restrict__ el,
    const float* __restrict__ er, unsigned short* __restrict__ outx,
    unsigned int* __restrict__ outb, float* __restrict__ wE, int init_w, int n)
{
  constexpr int LL = MDIM / 8;
  constexpr int EP = 64 / LL;
  constexpr int RS = MDIM / 8;
  __shared__ float alds[128 * HNUM];
  __shared__ int   sids[128];
  int node = blockIdx.x;
  if (node >= n) return;
  int lane = threadIdx.x;
  int base = ptre[node];
  int deg  = ptre[node + 1] - base;

  float erv[HNUM];
  if (HNUM == 4){
    float4 t = *reinterpret_cast<const float4*>(er + node * 4);
    erv[0] = t.x; erv[1] = t.y; erv[2] = t.z; erv[3] = t.w;
  } else erv[0] = er[node];

  float mx[HNUM], sm[HNUM];
#pragma unroll
  for (int h = 0; h < HNUM; h++){ mx[h] = -INFINITY; sm[h] = 0.f; }
  for (int i = lane; i < deg; i += 64){
    int s = srcs[base + i];
    float e[HNUM];
    if (HNUM == 4){
      float4 t = *reinterpret_cast<const float4*>(el + s * 4);
      e[0] = t.x; e[1] = t.y; e[2] = t.z; e[3] = t.w;
    } else e[0] = el[s];
#pragma unroll
    for (int h = 0; h < HNUM; h++){
      float v = e[h] + erv[h];
      v = v > 0.f ? v : 0.2f * v;
      float mn = fmaxf(mx[h], v);
      sm[h] = sm[h] * __expf(mx[h] - mn) + __expf(v - mn);
      mx[h] = mn;
    }
  }
  float M[HNUM], inv[HNUM];
#pragma unroll
  for (int h = 0; h < HNUM; h++){
    M[h] = wmaxf(mx[h]);
    float sc = sm[h] * __expf(mx[h] - M[h]);
    inv[h] = 1.f / (wsumf(sc) + 1e-9f);
  }

  int l = lane % LL, g = lane / LL;
  float acc[8];
#pragma unroll
  for (int d = 0; d < 8; d++) acc[d] = 0.f;

  for (int c0 = 0; c0 < deg; c0 += 128){
    int cnt = min(128, deg - c0);
    for (int i = lane; i < cnt; i += 64){
      int s = srcs[base + c0 + i];
      sids[i] = s;
      float e[HNUM], a[HNUM], wsum = 0.f;
      if (HNUM == 4){
        float4 t = *reinterpret_cast<const float4*>(el + s * 4);
        e[0] = t.x; e[1] = t.y; e[2] = t.z; e[3] = t.w;
      } else e[0] = el[s];
#pragma unroll
      for (int h = 0; h < HNUM; h++){
        float v = e[h] + erv[h];
        v = v > 0.f ? v : 0.2f * v;
        a[h] = __expf(v - M[h]) * inv[h];
        wsum += a[h];
      }
      if (HNUM == 4)
        *reinterpret_cast<float4*>(&alds[i * 4]) = make_float4(a[0], a[1], a[2], a[3]);
      else
        alds[i] = a[0];
      wsum *= (1.f / (3.f * HNUM));
      int eidx = base + c0 + i;
      wE[eidx] = init_w ? wsum : (wE[eidx] + wsum);
    }
    __syncthreads();
    for (int j0 = 0; j0 < cnt; j0 += EP){
      int j = j0 + g;
      if (j < cnt){
        int s = sids[j];
        float a = (HNUM == 4) ? alds[j * 4 + (l >> 2)] : alds[j];
        uint4 v = hb[(size_t)s * RS + l];
        acc[0] += a * bflo(v.x); acc[1] += a * bfhi(v.x);
        acc[2] += a * bflo(v.y); acc[3] += a * bfhi(v.y);
        acc[4] += a * bflo(v.z); acc[5] += a * bfhi(v.z);
        acc[6] += a * bflo(v.w); acc[7] += a * bfhi(v.w);
      }
    }
    __syncthreads();
  }
#pragma unroll
  for (int off = LL; off < 64; off <<= 1)
#pragma unroll
    for (int d = 0; d < 8; d++) acc[d] += __shfl_xor(acc[d], off, 64);

  if (EPI == 0){
    if (g == 0){
      float o[8];
#pragma unroll
      for (int d = 0; d < 8; d++) o[d] = acc[d] > 0.f ? acc[d] : expm1f(acc[d]);
      uint4 pk = make_uint4(packbf2(o[0], o[1]), packbf2(o[2], o[3]),
                            packbf2(o[4], o[5]), packbf2(o[6], o[7]));
      reinterpret_cast<uint4*>(outx + (size_t)node * MDIM)[l] = pk;
    }
  } else {
    float m8 = acc[0];
#pragma unroll
    for (int d = 1; d < 8; d++) m8 = fmaxf(m8, acc[d]);
#pragma unroll
    for (int off = 1; off < 8; off <<= 1) m8 = fmaxf(m8, __shfl_xor(m8, off, 64));
    float p[8], s8 = 0.f;
#pragma unroll
    for (int d = 0; d < 8; d++){ p[d] = __expf(acc[d] - m8); s8 += p[d]; }
#pragma unroll
    for (int off = 1; off < 8; off <<= 1) s8 += __shfl_xor(s8, off, 64);
    float is = 1.f / s8;
    if (g == 0){
      uint4 pk;
      pk.x = packbf2(p[0] * is, p[1] * is);
      pk.y = packbf2(p[2] * is, p[3] * is);
      pk.z = packbf2(p[4] * is, p[5] * is);
      pk.w = packbf2(p[6] * is, p[7] * is);
      *reinterpret_cast<uint4*>((unsigned short*)outb + (size_t)node * 64 + 8 * l) = pk;
    }
  }
}

// ---------------- LP aggregation: agg[dst](bf16) = sum_e w[e]*pseudo[src] ---
__global__ __launch_bounds__(256) void k_agg(
    const int* __restrict__ ptre, const int2* __restrict__ epk,
    const uint4* __restrict__ pb, unsigned short* __restrict__ aggb, int n)
{
  int w = threadIdx.x >> 6, lane = threadIdx.x & 63;
  int node = blockIdx.x * 4 + w;
  if (node >= n) return;
  int l = lane & 7, g = lane >> 3;
  int base = ptre[node], deg = ptre[node + 1] - base;
  float acc[8];
#pragma unroll
  for (int d = 0; d < 8; d++) acc[d] = 0.f;
  for (int j0 = 0; j0 < deg; j0 += 8){
    int j = j0 + g;
    if (j < deg){
      int2 ep = epk[base + j];
      float wv = __int_as_float(ep.y);
      uint4 v = pb[(size_t)ep.x * 8 + l];
      acc[0] += wv * bflo(v.x); acc[1] += wv * bfhi(v.x);
      acc[2] += wv * bflo(v.y); acc[3] += wv * bfhi(v.y);
      acc[4] += wv * bflo(v.z); acc[5] += wv * bfhi(v.z);
      acc[6] += wv * bflo(v.w); acc[7] += wv * bfhi(v.w);
    }
  }
#pragma unroll
  for (int off = 8; off < 64; off <<= 1)
#pragma unroll
    for (int d = 0; d < 8; d++) acc[d] += __shfl_xor(acc[d], off, 64);
  if (g == 0){
    uint4 pk = make_uint4(packbf2(acc[0], acc[1]), packbf2(acc[2], acc[3]),
                          packbf2(acc[4], acc[5]), packbf2(acc[6], acc[7]));
    reinterpret_cast<uint4*>(aggb + (size_t)node * 64)[l] = pk;
  }
}

// ---------------- launch ----------------
extern "C" void kernel_launch(void* const* d_in, const int* in_sizes, int n_in,
                              void* d_out, int out_size, void* d_ws, size_t ws_size,
                              hipStream_t stream) {
  const float* feat = (const float*)d_in[0];
  const int*   src  = (const int*)d_in[1];
  const int*   dst  = (const int*)d_in[2];
  const float* W0   = (const float*)d_in[3];
  const float* al0  = (const float*)d_in[4];
  const float* ar0  = (const float*)d_in[5];
  const float* W1   = (const float*)d_in[6];
  const float* al1  = (const float*)d_in[7];
  const float* ar1  = (const float*)d_in[8];
  const float* W2   = (const float*)d_in[9];
  const float* al2  = (const float*)d_in[10];
  const float* ar2  = (const float*)d_in[11];
  const float* Wp   = (const float*)d_in[12];
  const float* bp   = (const float*)d_in[13];
  float* out = (float*)d_out;

  const int N = in_sizes[0] / 256;
  const int E = in_sizes[1];
  const int NCH = (N + 255) / 256;

  char* p = (char*)d_ws;
  auto carve = [&](size_t bytes) -> void* {
    void* r = (void*)p;
    p += (bytes + 255) & ~(size_t)255;
    return r;
  };
  int*   ptr_i = (int*)carve((size_t)(N + 1) * 4);
  int*   cntA  = (int*)carve((size_t)N * 4);
  int*   cntB  = (int*)carve((size_t)N * 4);
  int*   sums  = (int*)carve(1024);
  int*   chof  = (int*)carve(1024);
  int*   srcs  = (int*)carve((size_t)E * 4);
  float* wE    = (float*)carve((size_t)E * 4);
  unsigned short* hb  = (unsigned short*)carve((size_t)N * 128 * 2);  // bf16 h
  unsigned short* xb  = (unsigned short*)carve((size_t)N * 128 * 2);  // bf16 ELU / epk overlay
  float* el    = (float*)carve((size_t)N * 4 * 4);
  float* er    = (float*)carve((size_t)N * 4 * 4);
  unsigned short* aggb = (unsigned short*)carve((size_t)N * 64 * 2);  // bf16 agg
  unsigned short* pbA  = (unsigned short*)carve((size_t)N * 64 * 2);  // bf16 pseudo
  unsigned short* pbB  = (unsigned short*)carve((size_t)N * 64 * 2);
  unsigned short* T0   = (unsigned short*)carve(32768 * 2);   // Wt0 [128][256]
  unsigned short* T1   = (unsigned short*)carve(16384 * 2);   // Wt1 [128][128]
  unsigned short* T2   = (unsigned short*)carve(8192 * 2);    // Wt2 [64][128]
  unsigned short* Tp   = (unsigned short*)carve(4096 * 2);    // Wtp [64][64]
  int2* epk = (int2*)xb;   // overlays xb (dead after layer-2 GEMM)
  (void)ws_size; (void)n_in; (void)out_size;

  // ---- CSR by dst + weight conversion ----
  k_zero2<<<(N + 255) / 256, 256, 0, stream>>>(cntA, cntB, N);
  k_hist<<<(E + 255) / 256, 256, 0, stream>>>(dst, cntA, E);
  k_scan1<<<NCH, 256, 0, stream>>>(cntA, ptr_i, sums, N);
  k_scan2<<<1, 256, 0, stream>>>(sums, chof, NCH);
  k_scan3<<<NCH, 256, 0, stream>>>(ptr_i, chof, N, E);
  k_fill<<<(E + 255) / 256, 256, 0, stream>>>(src, dst, ptr_i, cntB, srcs, E);
  k_cvtw<<<240, 256, 0, stream>>>(W0, W1, W2, Wp, T0, T1, T2, Tp);

  const int GG = (N + 63) / 64;
  // ---- layer 0: 256 -> [4,32] ----
  k_gemm_m<128, 0, true><<<GG, 256, 0, stream>>>(feat, T0, nullptr, hb, nullptr, N, 256);
  k_elr<4, 32><<<(N * 4 + 255) / 256, 256, 0, stream>>>(hb, al0, ar0, el, er, N);
  k_edge<4, 128, 0><<<N, 64, 0, stream>>>(ptr_i, srcs, (const uint4*)hb, el, er, xb, nullptr, wE, 1, N);
  // ---- layer 1: 128 -> [4,32] ----
  k_gemm_m<128, 0, false><<<GG, 256, 0, stream>>>(xb, T1, nullptr, hb, nullptr, N, 128);
  k_elr<4, 32><<<(N * 4 + 255) / 256, 256, 0, stream>>>(hb, al1, ar1, el, er, N);
  k_edge<4, 128, 0><<<N, 64, 0, stream>>>(ptr_i, srcs, (const uint4*)hb, el, er, xb, nullptr, wE, 0, N);
  // ---- layer 2: 128 -> [1,64] ----
  k_gemm_m<64, 0, false><<<GG, 256, 0, stream>>>(xb, T2, nullptr, hb, nullptr, N, 128);
  k_elr<1, 64><<<(N + 255) / 256, 256, 0, stream>>>(hb, al2, ar2, el, er, N);
  k_edge<1, 64, 1><<<N, 64, 0, stream>>>(ptr_i, srcs, (const uint4*)hb, el, er, nullptr,
                                         (unsigned int*)pbA, wE, 0, N);

  // ---- pack (src, w) for LP gathers (epk overlays xb, now dead) ----
  k_pack<<<(E + 255) / 256, 256, 0, stream>>>(srcs, wE, epk, E);

  // ---- 10 label-prop steps: bf16 gather-agg + MFMA linear + softmax -------
  unsigned short* cur = pbA; unsigned short* nxt = pbB;
  for (int st = 0; st < 10; st++){
    k_agg<<<(N + 3) / 4, 256, 0, stream>>>(ptr_i, epk, (const uint4*)cur, aggb, N);
    if (st == 9)
      k_gemm_m<64, 2, false><<<GG, 256, 0, stream>>>(aggb, Tp, bp, nullptr, out, N, 64);
    else
      k_gemm_m<64, 1, false><<<GG, 256, 0, stream>>>(aggb, Tp, bp, nxt, nullptr, N, 64);
    unsigned short* t = cur; cur = nxt; nxt = t;
  }
}

// Round 6
// 680.234 us; speedup vs baseline: 1.4218x; 1.0381x over previous
//
#include <hip/hip_runtime.h>
#include <math.h>

typedef _Float16 half_t;
typedef __attribute__((ext_vector_type(2))) _Float16 half2t;
typedef __attribute__((ext_vector_type(8))) _Float16 half8;
typedef __attribute__((ext_vector_type(4))) float f32x4;

// ---------------- fp16 helpers ----------------
__device__ __forceinline__ half2t u2h2(unsigned u){ half2t h; __builtin_memcpy(&h, &u, 4); return h; }
__device__ __forceinline__ unsigned h22u(half2t h){ unsigned u; __builtin_memcpy(&u, &h, 4); return u; }
__device__ __forceinline__ unsigned packh2(float a, float b){
  half2t h; h[0] = (_Float16)a; h[1] = (_Float16)b; return h22u(h);
}

// ---------------- wave helpers (wave = 64 on gfx950) ----------------
__device__ __forceinline__ float wmaxf(float v){
#pragma unroll
  for (int off = 1; off < 64; off <<= 1) v = fmaxf(v, __shfl_xor(v, off, 64));
  return v;
}
__device__ __forceinline__ float wsumf(float v){
#pragma unroll
  for (int off = 1; off < 64; off <<= 1) v += __shfl_xor(v, off, 64);
  return v;
}

// ---------------- CSR build ----------------
__global__ void k_zero2(int* __restrict__ a, int* __restrict__ b, int n){
  int i = blockIdx.x * blockDim.x + threadIdx.x;
  if (i < n){ a[i] = 0; b[i] = 0; }
}

__global__ void k_hist(const int* __restrict__ dst, int* __restrict__ cnt, int E){
  int i = blockIdx.x * blockDim.x + threadIdx.x;
  if (i < E) atomicAdd(&cnt[dst[i]], 1);
}

__global__ void k_scan1(const int* __restrict__ cnt, int* __restrict__ ptre,
                        int* __restrict__ sums, int n){
  __shared__ int sh[256];
  int t = threadIdx.x; int i = blockIdx.x * 256 + t;
  int v = (i < n) ? cnt[i] : 0;
  sh[t] = v; __syncthreads();
  for (int off = 1; off < 256; off <<= 1){
    int u = (t >= off) ? sh[t - off] : 0;
    __syncthreads();
    sh[t] += u;
    __syncthreads();
  }
  if (i < n) ptre[i] = sh[t] - v;
  if (t == 255) sums[blockIdx.x] = sh[255];
}

__global__ void k_scan2(const int* __restrict__ sums, int* __restrict__ chof, int nch){
  __shared__ int sh[256];
  int t = threadIdx.x;
  int v = (t < nch) ? sums[t] : 0;
  sh[t] = v; __syncthreads();
  for (int off = 1; off < 256; off <<= 1){
    int u = (t >= off) ? sh[t - off] : 0;
    __syncthreads();
    sh[t] += u;
    __syncthreads();
  }
  if (t < nch) chof[t] = sh[t] - v;
}

__global__ void k_scan3(int* __restrict__ ptre, const int* __restrict__ chof, int n, int E){
  int i = blockIdx.x * 256 + threadIdx.x;
  if (i < n) ptre[i] += chof[blockIdx.x];
  if (blockIdx.x == 0 && threadIdx.x == 0) ptre[n] = E;
}

__global__ void k_fill(const int* __restrict__ src, const int* __restrict__ dst,
                       const int* __restrict__ ptre, int* __restrict__ fpos,
                       int* __restrict__ srcs, int E){
  int i = blockIdx.x * blockDim.x + threadIdx.x;
  if (i < E){
    int d = dst[i];
    int pos = ptre[d] + atomicAdd(&fpos[d], 1);
    srcs[pos] = src[i];
  }
}

// pack (src, half2(w,w)) for LP gathers
__global__ void k_pack(const int* __restrict__ srcs, const float* __restrict__ wE,
                       int2* __restrict__ epk, int E){
  int i = blockIdx.x * blockDim.x + threadIdx.x;
  if (i < E){
    float w = wE[i];
    epk[i] = make_int2(srcs[i], (int)packh2(w, w));
  }
}

// ---------------- weight convert + transpose to fp16 [N][K] ----------------
__global__ void k_cvtw(const float* __restrict__ W0, const float* __restrict__ W1,
                       const float* __restrict__ W2, const float* __restrict__ Wp,
                       half_t* __restrict__ T0, half_t* __restrict__ T1,
                       half_t* __restrict__ T2, half_t* __restrict__ Tp){
  int i = blockIdx.x * 256 + threadIdx.x;
  const float* src; half_t* dst; int NN, KK, idx;
  if (i < 32768){ src = W0; dst = T0; NN = 128; KK = 256; idx = i; }
  else if (i < 49152){ src = W1; dst = T1; NN = 128; KK = 128; idx = i - 32768; }
  else if (i < 57344){ src = W2; dst = T2; NN = 64; KK = 128; idx = i - 49152; }
  else { src = Wp; dst = Tp; NN = 64; KK = 64; idx = i - 57344; }
  int nn = idx / KK, kk = idx - nn * KK;
  dst[idx] = (_Float16)src[(size_t)kk * NN + nn];
}

// ---------------- MFMA GEMM: Y[n,NC] = X[n,KD] @ W[KD,NC] -------------------
// X fp16 (or fp32 when XF32, converted in staging), Wt fp16 transposed [NC][KD].
// EPI 0: fp16 store; EPI 1: +bias row softmax -> fp16; EPI 2: +bias row
// log-softmax -> fp32 (NC=64 for EPI>0).
template<int NC, int EPI, bool XF32>
__global__ __launch_bounds__(256) void k_gemm_m(
    const void* __restrict__ Xv, const half_t* __restrict__ Wt,
    const float* __restrict__ bias, half_t* __restrict__ Yh,
    float* __restrict__ Yf, int n, int KD)
{
  constexpr int CT = NC / 16;
  __shared__ __align__(16) half_t xs[64 * 72];
  __shared__ __align__(16) half_t ws[NC * 72];
  __shared__ float bsh[64];
  int tid = threadIdx.x;
  int w = tid >> 6, lane = tid & 63;
  int m = lane & 15, q = lane >> 4;
  int n0 = blockIdx.x * 64;
  f32x4 acc[CT];
#pragma unroll
  for (int ct = 0; ct < CT; ct++) acc[ct] = (f32x4){0.f, 0.f, 0.f, 0.f};
  if (EPI != 0 && tid < 64) bsh[tid] = bias[tid];

  for (int kc = 0; kc < KD; kc += 64){
    if (XF32){
      const float* X = (const float*)Xv;
#pragma unroll
      for (int s = tid; s < 512; s += 256){
        int r = s >> 3, off = (s & 7) * 8;
        int gr = min(n0 + r, n - 1);
        const float4* g = (const float4*)(X + (size_t)gr * KD + kc + off);
        float4 v0 = g[0], v1 = g[1];
        uint4 pk = make_uint4(packh2(v0.x, v0.y), packh2(v0.z, v0.w),
                              packh2(v1.x, v1.y), packh2(v1.z, v1.w));
        *(uint4*)&xs[r * 72 + off] = pk;
      }
    } else {
      const half_t* X = (const half_t*)Xv;
#pragma unroll
      for (int s = tid; s < 512; s += 256){
        int r = s >> 3, off = (s & 7) * 8;
        int gr = min(n0 + r, n - 1);
        *(uint4*)&xs[r * 72 + off] = *(const uint4*)(X + (size_t)gr * KD + kc + off);
      }
    }
#pragma unroll
    for (int s = tid; s < NC * 8; s += 256){
      int r = s >> 3, off = (s & 7) * 8;
      *(uint4*)&ws[r * 72 + off] = *(const uint4*)(Wt + (size_t)r * KD + kc + off);
    }
    __syncthreads();
    half8 a0 = *(const half8*)&xs[(16 * w + m) * 72 + q * 8];
    half8 a1 = *(const half8*)&xs[(16 * w + m) * 72 + 32 + q * 8];
#pragma unroll
    for (int ct = 0; ct < CT; ct++){
      half8 b0 = *(const half8*)&ws[(16 * ct + m) * 72 + q * 8];
      half8 b1 = *(const half8*)&ws[(16 * ct + m) * 72 + 32 + q * 8];
      acc[ct] = __builtin_amdgcn_mfma_f32_16x16x32_f16(a0, b0, acc[ct], 0, 0, 0);
      acc[ct] = __builtin_amdgcn_mfma_f32_16x16x32_f16(a1, b1, acc[ct], 0, 0, 0);
    }
    __syncthreads();
  }

  if (EPI == 0){
#pragma unroll
    for (int j = 0; j < 4; j++){
      int gr = n0 + 16 * w + q * 4 + j;
      if (gr < n){
#pragma unroll
        for (int ct = 0; ct < CT; ct++)
          Yh[(size_t)gr * NC + 16 * ct + m] = (_Float16)acc[ct][j];
      }
    }
  } else {
#pragma unroll
    for (int j = 0; j < 4; j++){
      int gr = n0 + 16 * w + q * 4 + j;
      float v[CT];
      float mx = -INFINITY;
#pragma unroll
      for (int ct = 0; ct < CT; ct++){
        v[ct] = acc[ct][j] + bsh[16 * ct + m];
        mx = fmaxf(mx, v[ct]);
      }
#pragma unroll
      for (int off = 1; off < 16; off <<= 1) mx = fmaxf(mx, __shfl_xor(mx, off, 64));
      float p[CT], s = 0.f;
#pragma unroll
      for (int ct = 0; ct < CT; ct++){ p[ct] = __expf(v[ct] - mx); s += p[ct]; }
#pragma unroll
      for (int off = 1; off < 16; off <<= 1) s += __shfl_xor(s, off, 64);
      if (gr < n){
        if (EPI == 1){
          float is = 1.f / s;
#pragma unroll
          for (int ct = 0; ct < CT; ct++)
            Yh[(size_t)gr * 64 + 16 * ct + m] = (_Float16)(p[ct] * is);
        } else {
          float ls = __logf(s);
#pragma unroll
          for (int ct = 0; ct < CT; ct++)
            Yf[(size_t)gr * 64 + 16 * ct + m] = v[ct] - mx - ls;
        }
      }
    }
  }
}

// ---------------- el/er from fp16 h ----------------
template<int HNUM, int HIDD>
__global__ void k_elr(const half_t* __restrict__ hb, const float* __restrict__ al,
                      const float* __restrict__ ar, float* __restrict__ el,
                      float* __restrict__ er, int n)
{
  int idx = blockIdx.x * blockDim.x + threadIdx.x;
  if (idx >= n * HNUM) return;
  int node = idx / HNUM, hh = idx - node * HNUM;
  const uint2* row = reinterpret_cast<const uint2*>(hb + (size_t)node * (HNUM * HIDD) + hh * HIDD);
  const float4* a4 = reinterpret_cast<const float4*>(al + hh * HIDD);
  const float4* r4 = reinterpret_cast<const float4*>(ar + hh * HIDD);
  float se = 0.f, sr = 0.f;
#pragma unroll
  for (int d = 0; d < HIDD / 4; d++){
    uint2 u = row[d];
    half2t h0 = u2h2(u.x), h1 = u2h2(u.y);
    float v0 = (float)h0[0], v1 = (float)h0[1], v2 = (float)h1[0], v3 = (float)h1[1];
    float4 x = a4[d], y = r4[d];
    se += v0 * x.x + v1 * x.y + v2 * x.z + v3 * x.w;
    sr += v0 * y.x + v1 * y.y + v2 * y.z + v3 * y.w;
  }
  el[idx] = se; er[idx] = sr;
}

// ---------------- edge softmax + aggregation (one wave per dst node) --------
// fp16 h gathers, packed v_pk_fma_f16 accumulate. e-values cached in LDS for
// the first 256 edges (single el pass for deg<=256).
// EPI 0: ELU -> fp16 [N,MDIM]; EPI 1: softmax -> fp16 pseudo [N,64].
template<int HNUM, int MDIM, int EPI>
__global__ __launch_bounds__(64) void k_edge(
    const int* __restrict__ ptre, const int* __restrict__ srcs,
    const uint4* __restrict__ hb, const float* __restrict__ el,
    const float* __restrict__ er, half_t* __restrict__ outx,
    unsigned* __restrict__ outb, float* __restrict__ wE, int init_w, int n)
{
  constexpr int LL = MDIM / 8;     // lanes per edge (16 or 8)
  constexpr int EP = 64 / LL;      // edges in parallel (4 or 8)
  constexpr int RS = MDIM / 8;     // uint4 per row
  constexpr int HID = MDIM / HNUM;
  __shared__ unsigned au[256 * HNUM];   // e-bits, then alpha half2(a,a)
  __shared__ int sids[256];
  int node = blockIdx.x;
  if (node >= n) return;
  int lane = threadIdx.x;
  int base = ptre[node], deg = ptre[node + 1] - base;

  float erv[HNUM];
  if (HNUM == 4){
    float4 t = *reinterpret_cast<const float4*>(er + node * 4);
    erv[0] = t.x; erv[1] = t.y; erv[2] = t.z; erv[3] = t.w;
  } else erv[0] = er[node];

  // single pass: online max+sum, cache post-leaky e in LDS (i<256)
  float mx[HNUM], sm[HNUM];
#pragma unroll
  for (int h = 0; h < HNUM; h++){ mx[h] = -INFINITY; sm[h] = 0.f; }
  for (int i = lane; i < deg; i += 64){
    int s = srcs[base + i];
    if (i < 256) sids[i] = s;
    float e[HNUM];
    if (HNUM == 4){
      float4 t = *reinterpret_cast<const float4*>(el + s * 4);
      e[0] = t.x; e[1] = t.y; e[2] = t.z; e[3] = t.w;
    } else e[0] = el[s];
#pragma unroll
    for (int h = 0; h < HNUM; h++){
      float v = e[h] + erv[h];
      v = v > 0.f ? v : 0.2f * v;
      if (i < 256) au[i * HNUM + h] = __float_as_uint(v);
      float mn = fmaxf(mx[h], v);
      sm[h] = sm[h] * __expf(mx[h] - mn) + __expf(v - mn);
      mx[h] = mn;
    }
  }
  float M[HNUM], inv[HNUM];
#pragma unroll
  for (int h = 0; h < HNUM; h++){
    M[h] = wmaxf(mx[h]);
    float sc = sm[h] * __expf(mx[h] - M[h]);
    inv[h] = 1.f / (wsumf(sc) + 1e-9f);
  }

  int l = lane % LL, g = lane / LL;
  int hidx = (8 * l) / HID;
  half2t acc2[4];
#pragma unroll
  for (int k = 0; k < 4; k++) acc2[k] = (half2t){(_Float16)0.f, (_Float16)0.f};

  for (int c0 = 0; c0 < deg; c0 += 256){
    int cnt = min(256, deg - c0);
    for (int i = lane; i < cnt; i += 64){
      float v[HNUM];
      if (c0 == 0){
#pragma unroll
        for (int h = 0; h < HNUM; h++) v[h] = __uint_as_float(au[i * HNUM + h]);
      } else {
        int s = srcs[base + c0 + i];
        sids[i] = s;
        float e[HNUM];
        if (HNUM == 4){
          float4 t = *reinterpret_cast<const float4*>(el + s * 4);
          e[0] = t.x; e[1] = t.y; e[2] = t.z; e[3] = t.w;
        } else e[0] = el[s];
#pragma unroll
        for (int h = 0; h < HNUM; h++){
          float u = e[h] + erv[h];
          v[h] = u > 0.f ? u : 0.2f * u;
        }
      }
      float wsum = 0.f;
#pragma unroll
      for (int h = 0; h < HNUM; h++){
        float a = __expf(v[h] - M[h]) * inv[h];
        wsum += a;
        au[i * HNUM + h] = packh2(a, a);
      }
      wsum *= (1.f / (3.f * HNUM));
      int eidx = base + c0 + i;
      wE[eidx] = init_w ? wsum : (wE[eidx] + wsum);
    }
    __syncthreads();
    for (int j0 = 0; j0 < cnt; j0 += EP){
      int j = j0 + g;
      if (j < cnt){
        int s = sids[j];
        half2t a2 = u2h2(au[j * HNUM + hidx]);
        uint4 v = hb[(size_t)s * RS + l];
        acc2[0] += a2 * u2h2(v.x);
        acc2[1] += a2 * u2h2(v.y);
        acc2[2] += a2 * u2h2(v.z);
        acc2[3] += a2 * u2h2(v.w);
      }
    }
    __syncthreads();
  }
#pragma unroll
  for (int off = LL; off < 64; off <<= 1)
#pragma unroll
    for (int k = 0; k < 4; k++)
      acc2[k] += u2h2((unsigned)__shfl_xor((int)h22u(acc2[k]), off, 64));

  float o[8];
#pragma unroll
  for (int k = 0; k < 4; k++){
    o[2 * k] = (float)acc2[k][0];
    o[2 * k + 1] = (float)acc2[k][1];
  }
  if (EPI == 0){
    if (g == 0){
#pragma unroll
      for (int d = 0; d < 8; d++) o[d] = o[d] > 0.f ? o[d] : expm1f(o[d]);
      uint4 pk = make_uint4(packh2(o[0], o[1]), packh2(o[2], o[3]),
                            packh2(o[4], o[5]), packh2(o[6], o[7]));
      reinterpret_cast<uint4*>(outx + (size_t)node * MDIM)[l] = pk;
    }
  } else {
    float m8 = o[0];
#pragma unroll
    for (int d = 1; d < 8; d++) m8 = fmaxf(m8, o[d]);
#pragma unroll
    for (int off = 1; off < 8; off <<= 1) m8 = fmaxf(m8, __shfl_xor(m8, off, 64));
    float p[8], s8 = 0.f;
#pragma unroll
    for (int d = 0; d < 8; d++){ p[d] = __expf(o[d] - m8); s8 += p[d]; }
#pragma unroll
    for (int off = 1; off < 8; off <<= 1) s8 += __shfl_xor(s8, off, 64);
    float is = 1.f / s8;
    if (g == 0){
      uint4 pk = make_uint4(packh2(p[0] * is, p[1] * is), packh2(p[2] * is, p[3] * is),
                            packh2(p[4] * is, p[5] * is), packh2(p[6] * is, p[7] * is));
      *reinterpret_cast<uint4*>((half_t*)outb + (size_t)node * 64 + 8 * l) = pk;
    }
  }
}

// ---------------- LP aggregation: agg[dst](fp16) = sum_e w[e]*pseudo[src] ---
__global__ __launch_bounds__(256) void k_agg(
    const int* __restrict__ ptre, const int2* __restrict__ epk,
    const uint4* __restrict__ pb, half_t* __restrict__ aggb, int n)
{
  int w = threadIdx.x >> 6, lane = threadIdx.x & 63;
  int node = blockIdx.x * 4 + w;
  if (node >= n) return;
  int l = lane & 7, g = lane >> 3;
  int base = ptre[node], deg = ptre[node + 1] - base;
  half2t acc2[4];
#pragma unroll
  for (int k = 0; k < 4; k++) acc2[k] = (half2t){(_Float16)0.f, (_Float16)0.f};
  for (int j0 = 0; j0 < deg; j0 += 8){
    int j = j0 + g;
    if (j < deg){
      int2 ep = epk[base + j];
      half2t a2 = u2h2((unsigned)ep.y);
      uint4 v = pb[(size_t)ep.x * 8 + l];
      acc2[0] += a2 * u2h2(v.x);
      acc2[1] += a2 * u2h2(v.y);
      acc2[2] += a2 * u2h2(v.z);
      acc2[3] += a2 * u2h2(v.w);
    }
  }
#pragma unroll
  for (int off = 8; off < 64; off <<= 1)
#pragma unroll
    for (int k = 0; k < 4; k++)
      acc2[k] += u2h2((unsigned)__shfl_xor((int)h22u(acc2[k]), off, 64));
  if (g == 0){
    uint4 pk = make_uint4(h22u(acc2[0]), h22u(acc2[1]), h22u(acc2[2]), h22u(acc2[3]));
    reinterpret_cast<uint4*>(aggb + (size_t)node * 64)[l] = pk;
  }
}

// ---------------- launch ----------------
extern "C" void kernel_launch(void* const* d_in, const int* in_sizes, int n_in,
                              void* d_out, int out_size, void* d_ws, size_t ws_size,
                              hipStream_t stream) {
  const float* feat = (const float*)d_in[0];
  const int*   src  = (const int*)d_in[1];
  const int*   dst  = (const int*)d_in[2];
  const float* W0   = (const float*)d_in[3];
  const float* al0  = (const float*)d_in[4];
  const float* ar0  = (const float*)d_in[5];
  const float* W1   = (const float*)d_in[6];
  const float* al1  = (const float*)d_in[7];
  const float* ar1  = (const float*)d_in[8];
  const float* W2   = (const float*)d_in[9];
  const float* al2  = (const float*)d_in[10];
  const float* ar2  = (const float*)d_in[11];
  const float* Wp   = (const float*)d_in[12];
  const float* bp   = (const float*)d_in[13];
  float* out = (float*)d_out;

  const int N = in_sizes[0] / 256;
  const int E = in_sizes[1];
  const int NCH = (N + 255) / 256;

  char* p = (char*)d_ws;
  auto carve = [&](size_t bytes) -> void* {
    void* r = (void*)p;
    p += (bytes + 255) & ~(size_t)255;
    return r;
  };
  int*   ptr_i = (int*)carve((size_t)(N + 1) * 4);
  int*   cntA  = (int*)carve((size_t)N * 4);
  int*   cntB  = (int*)carve((size_t)N * 4);
  int*   sums  = (int*)carve(1024);
  int*   chof  = (int*)carve(1024);
  int*   srcs  = (int*)carve((size_t)E * 4);
  float* wE    = (float*)carve((size_t)E * 4);
  half_t* hb   = (half_t*)carve((size_t)N * 128 * 2);   // fp16 h
  half_t* xb   = (half_t*)carve((size_t)N * 128 * 2);   // fp16 ELU out / epk overlay
  float* el    = (float*)carve((size_t)N * 4 * 4);
  float* er    = (float*)carve((size_t)N * 4 * 4);
  half_t* aggb = (half_t*)carve((size_t)N * 64 * 2);    // fp16 agg
  half_t* pbA  = (half_t*)carve((size_t)N * 64 * 2);    // fp16 pseudo
  half_t* pbB  = (half_t*)carve((size_t)N * 64 * 2);
  half_t* T0   = (half_t*)carve(32768 * 2);   // Wt0 [128][256]
  half_t* T1   = (half_t*)carve(16384 * 2);   // Wt1 [128][128]
  half_t* T2   = (half_t*)carve(8192 * 2);    // Wt2 [64][128]
  half_t* Tp   = (half_t*)carve(4096 * 2);    // Wtp [64][64]
  int2* epk = (int2*)xb;   // overlays xb (dead after layer-2 GEMM)
  (void)ws_size; (void)n_in; (void)out_size;

  // ---- CSR by dst + weight conversion ----
  k_zero2<<<(N + 255) / 256, 256, 0, stream>>>(cntA, cntB, N);
  k_hist<<<(E + 255) / 256, 256, 0, stream>>>(dst, cntA, E);
  k_scan1<<<NCH, 256, 0, stream>>>(cntA, ptr_i, sums, N);
  k_scan2<<<1, 256, 0, stream>>>(sums, chof, NCH);
  k_scan3<<<NCH, 256, 0, stream>>>(ptr_i, chof, N, E);
  k_fill<<<(E + 255) / 256, 256, 0, stream>>>(src, dst, ptr_i, cntB, srcs, E);
  k_cvtw<<<240, 256, 0, stream>>>(W0, W1, W2, Wp, T0, T1, T2, Tp);

  const int GG = (N + 63) / 64;
  // ---- layer 0: 256 -> [4,32] ----
  k_gemm_m<128, 0, true><<<GG, 256, 0, stream>>>(feat, T0, nullptr, hb, nullptr, N, 256);
  k_elr<4, 32><<<(N * 4 + 255) / 256, 256, 0, stream>>>(hb, al0, ar0, el, er, N);
  k_edge<4, 128, 0><<<N, 64, 0, stream>>>(ptr_i, srcs, (const uint4*)hb, el, er, xb, nullptr, wE, 1, N);
  // ---- layer 1: 128 -> [4,32] ----
  k_gemm_m<128, 0, false><<<GG, 256, 0, stream>>>(xb, T1, nullptr, hb, nullptr, N, 128);
  k_elr<4, 32><<<(N * 4 + 255) / 256, 256, 0, stream>>>(hb, al1, ar1, el, er, N);
  k_edge<4, 128, 0><<<N, 64, 0, stream>>>(ptr_i, srcs, (const uint4*)hb, el, er, xb, nullptr, wE, 0, N);
  // ---- layer 2: 128 -> [1,64] ----
  k_gemm_m<64, 0, false><<<GG, 256, 0, stream>>>(xb, T2, nullptr, hb, nullptr, N, 128);
  k_elr<1, 64><<<(N + 255) / 256, 256, 0, stream>>>(hb, al2, ar2, el, er, N);
  k_edge<1, 64, 1><<<N, 64, 0, stream>>>(ptr_i, srcs, (const uint4*)hb, el, er, nullptr,
                                         (unsigned*)pbA, wE, 0, N);

  // ---- pack (src, half2(w,w)) for LP gathers (epk overlays xb, now dead) --
  k_pack<<<(E + 255) / 256, 256, 0, stream>>>(srcs, wE, epk, E);

  // ---- 10 label-prop steps: fp16 gather-agg + MFMA linear + softmax -------
  half_t* cur = pbA; half_t* nxt = pbB;
  for (int st = 0; st < 10; st++){
    k_agg<<<(N + 3) / 4, 256, 0, stream>>>(ptr_i, epk, (const uint4*)cur, aggb, N);
    if (st == 9)
      k_gemm_m<64, 2, false><<<GG, 256, 0, stream>>>(aggb, Tp, bp, nullptr, out, N, 64);
    else
      k_gemm_m<64, 1, false><<<GG, 256, 0, stream>>>(aggb, Tp, bp, nxt, nullptr, N, 64);
    half_t* t = cur; cur = nxt; nxt = t;
  }
}